// Round 3
// baseline (964.495 us; speedup 1.0000x reference)
//
#include <hip/hip_runtime.h>
#include <hip/hip_bf16.h>
#include <math.h>

#define DIM 1024
#define BATCH 16384
#define NLAYER 6

typedef __bf16 bf16_t;
typedef __attribute__((ext_vector_type(8))) __bf16 bf16x8;
typedef __attribute__((ext_vector_type(4))) float f32x4;

__device__ __forceinline__ void gload16(const void* g, void* l) {
  __builtin_amdgcn_global_load_lds(
      (const __attribute__((address_space(1))) void*)g,
      (__attribute__((address_space(3))) void*)l, 16, 0, 0);
}

__device__ __forceinline__ float fast_tanh(float x) {
  x = fminf(9.f, fmaxf(-9.f, x));
  const float e = __expf(x + x);
  return (e - 1.f) * __builtin_amdgcn_rcpf(e + 1.f);
}

__device__ __forceinline__ float bf2f(unsigned short u) {
  return __uint_as_float(((unsigned int)u) << 16);
}

// ---------------------------------------------------------------------------
// GEMM: C[m,n] = sum_k A[m,k] * W[n,k]  (A [BATCH x DIM] bf16, W [DIM x DIM])
// MODE 0: Tb = bf16( fast_tanh(scale[m]*C + b1[n]) )
// MODE 1: hb[m,n] = cf.w*hb_old + C + b2[n] + ce*e[n] + cc*c[n] + cn*nn[n]
//         + fused per-row stats partials (atomicAdd into sums[row][4])
// MODE 2: MODE1 + also write fp32 result to outF (final layer)
//
// K-loop: R0's proven 128x128 tile, BK=64, 4 waves (2x2), 4x4 of 16x16x32
// MFMA, single-buffered LDS + 2 syncthreads/tile, __launch_bounds__(256,4)
// -> 4 blocks/CU; cross-block wave overlap hides barrier drains (m114).
// DO NOT change to 1-block/CU structures: R1/R2 both regressed (61/75us
// vs 63us) because the implicit 4-block pipeline was lost.
// LDS XOR swizzle: phys_chunk = logical_chunk ^ (row & 7) (chunk = 16B),
// applied on the pre-swizzled GLOBAL source (gload_lds dest stays linear).
//
// Epilogue: per-wave LDS transpose (stride 68 f32; reuses sA/sB space after
// the final barrier, wave-private regions) so each lane owns one row x 16
// cols -> 16B coalesced global I/O for outB/hbIn/outF, and per-row stats
// reduce via 4-lane shfl + atomicAdd (replaces the stats_kernel pass).
//
// Block mapping: XCD-grouped (id%8 = XCD, each XCD gets a contiguous 16-row
// panel x all 8 col-blocks) so each XCD's L2 fetches its A-slice once.
// ---------------------------------------------------------------------------
template <int MODE>
__global__ __launch_bounds__(256, 4) void gemm_kernel(
    const bf16_t* __restrict__ A, const bf16_t* __restrict__ W,
    const float* __restrict__ bias, bf16_t* __restrict__ outB,
    float* __restrict__ outF, const f32x4* __restrict__ coef,
    const f32x4* __restrict__ colpack, const float* __restrict__ scaleArr,
    const bf16_t* __restrict__ hbIn, float* __restrict__ sums) {
  __shared__ __align__(16) char smem[34816];  // sA 16K | sB 16K | epi reuse
  bf16_t* sA = (bf16_t*)smem;
  bf16_t* sB = (bf16_t*)(smem + 16384);
  const int tid = threadIdx.x;
  const int w = tid >> 6;
  const int lane = tid & 63;
  // XCD-grouped bijective mapping: id = xcd + 8*(8*(bx&15) + by), bx = 16*xcd + ...
  const int id = blockIdx.x;
  const int xcd = id & 7;
  const int jj_ = id >> 3;              // 0..127
  const int bxi = (xcd << 4) + (jj_ >> 3);  // 0..127 (16-panel per XCD)
  const int byi = jj_ & 7;              // 0..7
  const int bm = bxi * 128;
  const int bn = byi * 128;
  const int wm = (w & 1) * 64;
  const int wn = (w >> 1) * 64;
  const int lm = lane & 15;
  const int lc = lane >> 4;  // 0..3

  f32x4 acc[4][4] = {};

  // staging: thread -> (row srow = tid>>3, phys chunk p = tid&7)
  // content at (row,p) = logical chunk p ^ (row&7).
  const int srow = tid >> 3;
  const int swz = ((tid & 7) ^ (srow & 7)) * 8;
  const bf16_t* gA = A + (size_t)(bm + srow) * DIM + swz;
  const bf16_t* gW = W + (size_t)(bn + srow) * DIM + swz;
  char* lA = (char*)sA + w * 1024;  // wave-uniform base (lane*16 implied)
  char* lB = (char*)sB + w * 1024;

  for (int kt = 0; kt < DIM; kt += 64) {
#pragma unroll
    for (int q = 0; q < 4; ++q) {
      gload16(gA + kt + (size_t)q * 32 * DIM, lA + q * 4096);
      gload16(gW + kt + (size_t)q * 32 * DIM, lB + q * 4096);
    }
    __syncthreads();  // drain staging
#pragma unroll
    for (int kh = 0; kh < 2; ++kh) {
      bf16x8 aF[4], bF[4];
      const int lgc = kh * 4 + lc;
#pragma unroll
      for (int i = 0; i < 4; ++i) {
        const int rowA = wm + i * 16 + lm;
        aF[i] = *(const bf16x8*)((char*)sA + rowA * 128 +
                                 ((lgc ^ (lm & 7)) << 4));
      }
#pragma unroll
      for (int j = 0; j < 4; ++j) {
        const int rowB = wn + j * 16 + lm;
        bF[j] = *(const bf16x8*)((char*)sB + rowB * 128 +
                                 ((lgc ^ (lm & 7)) << 4));
      }
#pragma unroll
      for (int i = 0; i < 4; ++i)
#pragma unroll
        for (int j = 0; j < 4; ++j)
          acc[i][j] = __builtin_amdgcn_mfma_f32_16x16x32_bf16(
              aF[i], bF[j], acc[i][j], 0, 0, 0);
    }
    __syncthreads();  // protect LDS before next stage
  }

  // ---- epilogue: LDS transpose for coalesced global I/O ----
  // all waves passed the final barrier; epi regions are wave-private.
  // C/D layout: col = lane&15, row = (lane>>4)*4 + reg  [m89/m91]
  float* epi = (float*)(smem + w * 8704);  // 2 parity x 16x68 f32
  const int r0 = lc << 2;
  const int rr = lane >> 2;        // 0..15: row within 16-row block
  const int cc = (lane & 3) << 4;  // 0/16/32/48: col start within 64
  const int gcol = bn + wn + cc;

#pragma unroll
  for (int i = 0; i < 4; ++i) {
    float* eb = epi + (i & 1) * 1088;
#pragma unroll
    for (int j = 0; j < 4; ++j)
#pragma unroll
      for (int r = 0; r < 4; ++r)
        eb[(r0 + r) * 68 + (j << 4) + lm] = acc[i][j][r];
    asm volatile("s_waitcnt lgkmcnt(0)" ::: "memory");
    const float* src = eb + rr * 68 + cc;
    f32x4 v[4];
#pragma unroll
    for (int q = 0; q < 4; ++q) v[q] = *(const f32x4*)(src + 4 * q);

    const int grow = bm + wm + i * 16 + rr;
    if constexpr (MODE == 0) {
      const float s = scaleArr[grow];
      union { bf16_t b[16]; uint4 u[2]; } pk;
#pragma unroll
      for (int q = 0; q < 4; ++q) {
        const f32x4 bv = *(const f32x4*)(bias + gcol + 4 * q);
#pragma unroll
        for (int j = 0; j < 4; ++j)
          pk.b[4 * q + j] = (bf16_t)fast_tanh(s * v[q][j] + bv[j]);
      }
      uint4* dst = (uint4*)(outB + (size_t)grow * DIM + gcol);
      dst[0] = pk.u[0];
      dst[1] = pk.u[1];
    } else {
      const f32x4 cf = coef[grow];
      const bf16_t* hp = hbIn + (size_t)grow * DIM + gcol;
      union { bf16_t b[16]; uint4 u[2]; } hin;
      hin.u[0] = *(const uint4*)hp;
      hin.u[1] = *(const uint4*)(hp + 8);
      union { bf16_t b[16]; uint4 u[2]; } pk;
      float ss = 0.f, de = 0.f, dc = 0.f, dn = 0.f;
      f32x4 fo[4];
#pragma unroll
      for (int q = 0; q < 4; ++q)
#pragma unroll
        for (int j = 0; j < 4; ++j) {
          const int e = 4 * q + j;
          const f32x4 cp = colpack[gcol + e];  // {e, c, n, b2}
          const float val = v[q][j] + cp.w + cf.x * cp.x + cf.y * cp.y +
                            cf.z * cp.z + cf.w * (float)hin.b[e];
          pk.b[e] = (bf16_t)val;
          fo[q][j] = val;
          ss += val * val;
          de += val * cp.x;
          dc += val * cp.y;
          dn += val * cp.z;
        }
      uint4* dst = (uint4*)(outB + (size_t)grow * DIM + gcol);
      dst[0] = pk.u[0];
      dst[1] = pk.u[1];
      if constexpr (MODE == 2) {
#pragma unroll
        for (int q = 0; q < 4; ++q)
          *(f32x4*)(outF + (size_t)grow * DIM + gcol + 4 * q) = fo[q];
      }
      // per-row stats partials: reduce over the 4 lanes sharing this row
      ss += __shfl_xor(ss, 1); ss += __shfl_xor(ss, 2);
      de += __shfl_xor(de, 1); de += __shfl_xor(de, 2);
      dc += __shfl_xor(dc, 1); dc += __shfl_xor(dc, 2);
      dn += __shfl_xor(dn, 1); dn += __shfl_xor(dn, 2);
      if ((lane & 3) == 0) {
        float* sp = sums + (size_t)grow * 4;
        atomicAdd(sp + 0, ss);
        atomicAdd(sp + 1, de);
        atomicAdd(sp + 2, dc);
        atomicAdd(sp + 3, dn);
      }
    }
  }
}

// ---------------------------------------------------------------------------
// convert: sums[row] = {S, E, C, N} -> coef[row], scaleArr[row]; re-zero sums.
// Same math as the old stats tail (doClamp = 1).
// ---------------------------------------------------------------------------
__global__ __launch_bounds__(256) void convert_kernel(
    float* __restrict__ sums, f32x4* __restrict__ coef,
    float* __restrict__ scaleArr) {
  const int row = blockIdx.x * 256 + threadIdx.x;
  f32x4* sp = (f32x4*)(sums + (size_t)row * 4);
  const f32x4 s = *sp;
  f32x4 z = {};
  *sp = z;  // ready for next layer
  const float S = s.x, E = s.y, C = s.z, N = s.w;
  const float norm = sqrtf(S);
  float scale = 1.f;
  if (norm > 10.f) scale = 10.f / (norm + 1e-8f);
  const float invn = 1.f / fmaxf(norm, 1e-12f);
  const float ae = E * invn;
  const float ac = C * invn;
  const float an = N * invn;
  const float nc = norm * scale;
  const float re = sqrtf(fmaxf(nc * nc - 2.f * nc * ae + 1.f, 0.f));
  const float rc = sqrtf(fmaxf(nc * nc - 2.f * nc * ac + 1.f, 0.f));
  const float rn = sqrtf(fmaxf(nc * nc - 2.f * nc * an + 1.f, 0.f));
  const float boundary = fminf(fmaxf(1.f - fabsf(ae - ac), 0.f), 1.f);
  f32x4 cf;
  cf.x = 0.1f * (1.f - ae) / fmaxf(re, 1e-12f);
  cf.y = 0.1f * (1.f - ac) / fmaxf(rc, 1e-12f);
  cf.z = (0.05f * (1.f - an) + 0.05f * boundary) / fmaxf(rn, 1e-12f);
  cf.w = scale * (1.f - cf.x - cf.y - cf.z);
  coef[row] = cf;
  scaleArr[row] = scale;
}

__global__ __launch_bounds__(256) void zero_sums_kernel(
    float* __restrict__ sums) {
  const int i = blockIdx.x * 256 + threadIdx.x;
  f32x4 z = {};
  ((f32x4*)sums)[i] = z;
}

// ---------------------------------------------------------------------------
// Per-row stats for fp32 h0 (layer 0 only; also casts h0 -> hb bf16).
// ---------------------------------------------------------------------------
__global__ __launch_bounds__(256) void stats0_kernel(
    const float* __restrict__ src, bf16_t* __restrict__ dstb,
    float* __restrict__ scaleArr, f32x4* __restrict__ coef,
    const float* __restrict__ dirs) {
  const int row = blockIdx.x;
  const int t = threadIdx.x;
  const float4 v = ((const float4*)src)[(size_t)row * 256 + t];
  const float4 e = ((const float4*)dirs)[t];
  const float4 c = ((const float4*)dirs)[t + 256];
  const float4 n = ((const float4*)dirs)[t + 512];
  float ss = v.x * v.x + v.y * v.y + v.z * v.z + v.w * v.w;
  float de = v.x * e.x + v.y * e.y + v.z * e.z + v.w * e.w;
  float dc = v.x * c.x + v.y * c.y + v.z * c.z + v.w * c.w;
  float dn = v.x * n.x + v.y * n.y + v.z * n.z + v.w * n.w;
#pragma unroll
  for (int off = 32; off; off >>= 1) {
    ss += __shfl_down(ss, off);
    de += __shfl_down(de, off);
    dc += __shfl_down(dc, off);
    dn += __shfl_down(dn, off);
  }
  __shared__ float red[4][4];
  const int w = t >> 6;
  if ((t & 63) == 0) {
    red[w][0] = ss; red[w][1] = de; red[w][2] = dc; red[w][3] = dn;
  }
  __syncthreads();
  union { bf16_t b[4]; uint2 u; } pk;
  pk.b[0] = (bf16_t)v.x; pk.b[1] = (bf16_t)v.y;
  pk.b[2] = (bf16_t)v.z; pk.b[3] = (bf16_t)v.w;
  ((uint2*)dstb)[(size_t)row * 256 + t] = pk.u;
  if (t == 0) {
    float S = 0, E = 0, C = 0, N = 0;
#pragma unroll
    for (int i = 0; i < 4; ++i) {
      S += red[i][0]; E += red[i][1]; C += red[i][2]; N += red[i][3];
    }
    const float norm = sqrtf(S);
    const float scale = 1.f;  // no clamp on layer 0 input
    const float invn = 1.f / fmaxf(norm, 1e-12f);
    const float ae = E * invn;
    const float ac = C * invn;
    const float an = N * invn;
    const float nc = norm * scale;
    const float re = sqrtf(fmaxf(nc * nc - 2.f * nc * ae + 1.f, 0.f));
    const float rc = sqrtf(fmaxf(nc * nc - 2.f * nc * ac + 1.f, 0.f));
    const float rn = sqrtf(fmaxf(nc * nc - 2.f * nc * an + 1.f, 0.f));
    const float boundary = fminf(fmaxf(1.f - fabsf(ae - ac), 0.f), 1.f);
    f32x4 cf;
    cf.x = 0.1f * (1.f - ae) / fmaxf(re, 1e-12f);
    cf.y = 0.1f * (1.f - ac) / fmaxf(rc, 1e-12f);
    cf.z = (0.05f * (1.f - an) + 0.05f * boundary) / fmaxf(rn, 1e-12f);
    cf.w = scale * (1.f - cf.x - cf.y - cf.z);
    coef[row] = cf;
    scaleArr[row] = scale;
  }
}

__global__ __launch_bounds__(256) void finalize_kernel(
    float* __restrict__ outF, const float* __restrict__ scaleArr) {
  const int row = blockIdx.x;
  const int t = threadIdx.x;
  const float s = scaleArr[row];
  float4 v = ((float4*)outF)[(size_t)row * 256 + t];
  v.x *= s; v.y *= s; v.z *= s; v.w *= s;
  ((float4*)outF)[(size_t)row * 256 + t] = v;
}

// Normalize anchors -> dirs[3*DIM]
__global__ __launch_bounds__(256) void prep_dirs(
    const float* __restrict__ ae, const float* __restrict__ ac,
    const float* __restrict__ an, float* __restrict__ dirs) {
  const int t = threadIdx.x;
  const float4 a = ((const float4*)ae)[t];
  const float4 b = ((const float4*)ac)[t];
  const float4 c = ((const float4*)an)[t];
  float sa = a.x * a.x + a.y * a.y + a.z * a.z + a.w * a.w;
  float sb = b.x * b.x + b.y * b.y + b.z * b.z + b.w * b.w;
  float sc = c.x * c.x + c.y * c.y + c.z * c.z + c.w * c.w;
#pragma unroll
  for (int off = 32; off; off >>= 1) {
    sa += __shfl_down(sa, off);
    sb += __shfl_down(sb, off);
    sc += __shfl_down(sc, off);
  }
  __shared__ float red[4][3];
  __shared__ float fin[3];
  const int w = t >> 6;
  if ((t & 63) == 0) { red[w][0] = sa; red[w][1] = sb; red[w][2] = sc; }
  __syncthreads();
  if (t == 0) {
    float x = 0, y = 0, z = 0;
#pragma unroll
    for (int i = 0; i < 4; ++i) { x += red[i][0]; y += red[i][1]; z += red[i][2]; }
    fin[0] = x; fin[1] = y; fin[2] = z;
  }
  __syncthreads();
  const float ia = 1.f / fmaxf(sqrtf(fin[0]), 1e-12f);
  const float ib = 1.f / fmaxf(sqrtf(fin[1]), 1e-12f);
  const float ic = 1.f / fmaxf(sqrtf(fin[2]), 1e-12f);
  float4 oa, ob, oc;
  oa.x = a.x * ia; oa.y = a.y * ia; oa.z = a.z * ia; oa.w = a.w * ia;
  ob.x = b.x * ib; ob.y = b.y * ib; ob.z = b.z * ib; ob.w = b.w * ib;
  oc.x = c.x * ic; oc.y = c.y * ic; oc.z = c.z * ic; oc.w = c.w * ic;
  ((float4*)dirs)[t] = oa;
  ((float4*)dirs)[t + 256] = ob;
  ((float4*)dirs)[t + 512] = oc;
}

// Build colpack[col] = {e[col], c[col], n[col], b2[col]}
__global__ __launch_bounds__(256) void prep_cols(
    const float* __restrict__ dirs, const float* __restrict__ b2,
    f32x4* __restrict__ colpack) {
  const int t = threadIdx.x;  // handles cols 4t..4t+3
  const float4 e = ((const float4*)dirs)[t];
  const float4 c = ((const float4*)dirs)[t + 256];
  const float4 n = ((const float4*)dirs)[t + 512];
  const float4 b = ((const float4*)b2)[t];
  f32x4 o;
  o.x = e.x; o.y = c.x; o.z = n.x; o.w = b.x; colpack[4 * t + 0] = o;
  o.x = e.y; o.y = c.y; o.z = n.y; o.w = b.y; colpack[4 * t + 1] = o;
  o.x = e.z; o.y = c.z; o.z = n.z; o.w = b.z; colpack[4 * t + 2] = o;
  o.x = e.w; o.y = c.w; o.z = n.w; o.w = b.w; colpack[4 * t + 3] = o;
}

__global__ __launch_bounds__(256) void cast_w_kernel(
    const float* __restrict__ W, bf16_t* __restrict__ Wb) {
  const int i = blockIdx.x * 256 + threadIdx.x;
  const float4 v = ((const float4*)W)[i];
  union { bf16_t b[4]; uint2 u; } pk;
  pk.b[0] = (bf16_t)v.x; pk.b[1] = (bf16_t)v.y;
  pk.b[2] = (bf16_t)v.z; pk.b[3] = (bf16_t)v.w;
  ((uint2*)Wb)[i] = pk.u;
}

extern "C" void kernel_launch(void* const* d_in, const int* in_sizes, int n_in,
                              void* d_out, int out_size, void* d_ws,
                              size_t ws_size, hipStream_t stream) {
  const float* h0 = (const float*)d_in[0];
  const float* W1 = (const float*)d_in[1];
  const float* b1 = (const float*)d_in[2];
  const float* W2 = (const float*)d_in[3];
  const float* b2 = (const float*)d_in[4];
  const float* ae = (const float*)d_in[5];
  const float* ac = (const float*)d_in[6];
  const float* an = (const float*)d_in[7];
  float* outF = (float*)d_out;

  char* ws = (char*)d_ws;
  bf16_t* hb = (bf16_t*)ws;  ws += (size_t)BATCH * DIM * 2;   // 32 MB
  bf16_t* Tb = (bf16_t*)ws;  ws += (size_t)BATCH * DIM * 2;   // 32 MB
  bf16_t* W1b = (bf16_t*)ws; ws += (size_t)DIM * DIM * 2;     // 2 MB
  bf16_t* W2b = (bf16_t*)ws; ws += (size_t)DIM * DIM * 2;     // 2 MB
  float* dirs = (float*)ws;  ws += 3 * DIM * 4;
  f32x4* colpack = (f32x4*)ws; ws += DIM * 16;
  f32x4* coef = (f32x4*)ws;  ws += (size_t)BATCH * 16;
  float* scaleArr = (float*)ws; ws += (size_t)BATCH * 4;
  float* sums = (float*)ws;  ws += (size_t)BATCH * 16;        // 256 KB

  prep_dirs<<<1, 256, 0, stream>>>(ae, ac, an, dirs);
  prep_cols<<<1, 256, 0, stream>>>(dirs, b2, colpack);
  cast_w_kernel<<<DIM * DIM / 1024, 256, 0, stream>>>(W1, W1b);
  cast_w_kernel<<<DIM * DIM / 1024, 256, 0, stream>>>(W2, W2b);
  zero_sums_kernel<<<BATCH / 256, 256, 0, stream>>>(sums);
  stats0_kernel<<<BATCH, 256, 0, stream>>>(h0, hb, scaleArr, coef, dirs);

  const int grid = (BATCH / 128) * (DIM / 128);  // 1024 blocks, 1D
  for (int l = 0; l < NLAYER; ++l) {
    gemm_kernel<0><<<grid, 256, 0, stream>>>(hb, W1b, b1, Tb, nullptr, nullptr,
                                             nullptr, scaleArr, nullptr,
                                             nullptr);
    if (l < NLAYER - 1) {
      gemm_kernel<1><<<grid, 256, 0, stream>>>(Tb, W2b, b2, hb, nullptr, coef,
                                               colpack, nullptr, hb, sums);
      convert_kernel<<<BATCH / 256, 256, 0, stream>>>(sums, coef, scaleArr);
    } else {
      gemm_kernel<2><<<grid, 256, 0, stream>>>(Tb, W2b, b2, hb, outF, coef,
                                               colpack, nullptr, hb, sums);
      convert_kernel<<<BATCH / 256, 256, 0, stream>>>(sums, coef, scaleArr);
      finalize_kernel<<<BATCH, 256, 0, stream>>>(outF, scaleArr);
    }
  }
}

// Round 5
// 763.563 us; speedup vs baseline: 1.2632x; 1.2632x over previous
//
#include <hip/hip_runtime.h>
#include <hip/hip_bf16.h>
#include <math.h>

#define DIM 1024
#define BATCH 16384
#define NLAYER 6

typedef __bf16 bf16_t;
typedef __attribute__((ext_vector_type(8))) __bf16 bf16x8;
typedef __attribute__((ext_vector_type(4))) float f32x4;

__device__ __forceinline__ void gload16(const void* g, void* l) {
  __builtin_amdgcn_global_load_lds(
      (const __attribute__((address_space(1))) void*)g,
      (__attribute__((address_space(3))) void*)l, 16, 0, 0);
}

__device__ __forceinline__ float fast_tanh(float x) {
  x = fminf(9.f, fmaxf(-9.f, x));
  const float e = __expf(x + x);
  return (e - 1.f) * __builtin_amdgcn_rcpf(e + 1.f);
}

__device__ __forceinline__ float bf2f(unsigned short u) {
  return __uint_as_float(((unsigned int)u) << 16);
}

// ---------------------------------------------------------------------------
// GEMM: C[m,n] = sum_k A[m,k] * W[n,k]  (A [BATCH x DIM] bf16, W [DIM x DIM])
// MODE 0: Tb = bf16( fast_tanh(scale[m]*C + b1[n]) )
// MODE 1: hb[m,n] = cf.w*hb_old + C + b2[n] + ce*e[n] + cc*c[n] + cn*nn[n]
//         + per-row stats partials (plain f32x4 store, NO atomics)
// MODE 2: MODE1 math but writes fp32 outF ONLY (final layer; hb is dead)
//
// K-loop + MODE0 epilogue: R0's proven structure, bit-for-bit.
// 128x128 tile, BK=64, 4 waves (2x2), 4x4 of 16x16x32 MFMA, single-buffered
// LDS + 2 syncthreads/tile, __launch_bounds__(256,4) -> 4 blocks/CU; the
// cross-block wave overlap hides barrier drains (m114). R1/R2 1-block/CU
// restructures regressed; do not repeat.
// R3 lesson: fused stats via global atomicAdd cost +33MB WRITE (line-granular
// RMW write-through) and serialized cross-XCD -> partials+convert instead.
// R4 lesson: rows are covered by TWO waves (column halves wn=0/64), so each
// column half needs its OWN partial slot: part[row][16], slot = byi*2+(w>>1).
// LDS XOR swizzle: phys_chunk = logical_chunk ^ (row & 7)  (chunk = 16B)
// ---------------------------------------------------------------------------
template <int MODE>
__global__ __launch_bounds__(256, 4) void gemm_kernel(
    const bf16_t* __restrict__ A, const bf16_t* __restrict__ W,
    const float* __restrict__ bias, bf16_t* __restrict__ outB,
    float* __restrict__ outF, const f32x4* __restrict__ coef,
    const f32x4* __restrict__ colpack, const float* __restrict__ scaleArr,
    const bf16_t* __restrict__ hbIn, float* __restrict__ part) {
  __shared__ __align__(16) bf16_t sA[128 * 64];
  __shared__ __align__(16) bf16_t sB[128 * 64];
  const int tid = threadIdx.x;
  const int w = tid >> 6;
  const int lane = tid & 63;
  const int bm = blockIdx.x * 128;
  const int bn = blockIdx.y * 128;
  const int byi = blockIdx.y;
  const int wm = (w & 1) * 64;
  const int wn = (w >> 1) * 64;
  const int lm = lane & 15;
  const int lc = lane >> 4;  // 0..3

  f32x4 acc[4][4] = {};

  // staging: thread -> (row srow = tid>>3, phys chunk p = tid&7)
  // content at (row,p) = logical chunk p ^ (row&7).
  const int srow = tid >> 3;
  const int swz = ((tid & 7) ^ (srow & 7)) * 8;
  const bf16_t* gA = A + (size_t)(bm + srow) * DIM + swz;
  const bf16_t* gW = W + (size_t)(bn + srow) * DIM + swz;
  char* lA = (char*)sA + w * 1024;  // wave-uniform base (lane*16 implied)
  char* lB = (char*)sB + w * 1024;

  for (int kt = 0; kt < DIM; kt += 64) {
#pragma unroll
    for (int q = 0; q < 4; ++q) {
      gload16(gA + kt + (size_t)q * 32 * DIM, lA + q * 4096);
      gload16(gW + kt + (size_t)q * 32 * DIM, lB + q * 4096);
    }
    __syncthreads();  // drain staging
#pragma unroll
    for (int kh = 0; kh < 2; ++kh) {
      bf16x8 aF[4], bF[4];
      const int lgc = kh * 4 + lc;
#pragma unroll
      for (int i = 0; i < 4; ++i) {
        const int rowA = wm + i * 16 + lm;
        aF[i] = *(const bf16x8*)((char*)sA + rowA * 128 +
                                 ((lgc ^ (lm & 7)) << 4));
      }
#pragma unroll
      for (int j = 0; j < 4; ++j) {
        const int rowB = wn + j * 16 + lm;
        bF[j] = *(const bf16x8*)((char*)sB + rowB * 128 +
                                 ((lgc ^ (lm & 7)) << 4));
      }
#pragma unroll
      for (int i = 0; i < 4; ++i)
#pragma unroll
        for (int j = 0; j < 4; ++j)
          acc[i][j] = __builtin_amdgcn_mfma_f32_16x16x32_bf16(
              aF[i], bF[j], acc[i][j], 0, 0, 0);
    }
    __syncthreads();  // protect LDS before next stage
  }

  // C/D layout: col = lane&15, row = (lane>>4)*4 + reg  [m89/m91]
  const int r0 = lc << 2;
#pragma unroll
  for (int i = 0; i < 4; ++i) {
    const int rowBase = bm + wm + i * 16 + r0;
    if constexpr (MODE == 0) {
      float s4[4];
#pragma unroll
      for (int r = 0; r < 4; ++r) s4[r] = scaleArr[rowBase + r];
#pragma unroll
      for (int j = 0; j < 4; ++j) {
        const int col = bn + wn + j * 16 + lm;
        const float bv = bias[col];
#pragma unroll
        for (int r = 0; r < 4; ++r)
          outB[(size_t)(rowBase + r) * DIM + col] =
              (bf16_t)fast_tanh(s4[r] * acc[i][j][r] + bv);
      }
    } else {
      f32x4 cf[4];
#pragma unroll
      for (int r = 0; r < 4; ++r) cf[r] = coef[rowBase + r];
      float ss[4] = {}, de[4] = {}, dc[4] = {}, dn[4] = {};
#pragma unroll
      for (int j = 0; j < 4; ++j) {
        const int col = bn + wn + j * 16 + lm;
        const f32x4 cp = colpack[col];  // {e, c, n, b2}
#pragma unroll
        for (int r = 0; r < 4; ++r) {
          const size_t idx = (size_t)(rowBase + r) * DIM + col;
          const float hp = (float)hbIn[idx];
          const float v = acc[i][j][r] + cp.w + cf[r].x * cp.x +
                          cf[r].y * cp.y + cf[r].z * cp.z + cf[r].w * hp;
          if constexpr (MODE == 1) outB[idx] = (bf16_t)v;
          if constexpr (MODE == 2) outF[idx] = v;
          ss[r] += v * v;
          de[r] += v * cp.x;
          dc[r] += v * cp.y;
          dn[r] += v * cp.z;
        }
      }
      // reduce each row's partials across the 16 lanes (lm) sharing it;
      // xor masks 1/2/4/8 stay within the lm group (lc bits untouched).
      // slot = byi*2 + (w>>1): column half wn=0 -> +0, wn=64 -> +1 (R4 fix).
      const int slot = byi * 2 + (w >> 1);
#pragma unroll
      for (int r = 0; r < 4; ++r) {
        float a = ss[r], b = de[r], c = dc[r], d = dn[r];
#pragma unroll
        for (int mask = 1; mask < 16; mask <<= 1) {
          a += __shfl_xor(a, mask);
          b += __shfl_xor(b, mask);
          c += __shfl_xor(c, mask);
          d += __shfl_xor(d, mask);
        }
        if (lm == 0) {
          f32x4 o;
          o.x = a; o.y = b; o.z = c; o.w = d;
          ((f32x4*)part)[(size_t)(rowBase + r) * 16 + slot] = o;
        }
      }
    }
  }
}

// ---------------------------------------------------------------------------
// convert: sum the 16 partials per row -> coef[row], scaleArr[row]
// (same math as the old stats tail, doClamp = 1). part[row][16] f32x4.
// ---------------------------------------------------------------------------
__global__ __launch_bounds__(256) void convert_kernel(
    const float* __restrict__ part, f32x4* __restrict__ coef,
    float* __restrict__ scaleArr) {
  const int row = blockIdx.x * 256 + threadIdx.x;
  const f32x4* p = (const f32x4*)part + (size_t)row * 16;
  float S = 0.f, E = 0.f, C = 0.f, N = 0.f;
#pragma unroll
  for (int b = 0; b < 16; ++b) {
    const f32x4 v = p[b];
    S += v.x; E += v.y; C += v.z; N += v.w;
  }
  const float norm = sqrtf(S);
  float scale = 1.f;
  if (norm > 10.f) scale = 10.f / (norm + 1e-8f);
  const float invn = 1.f / fmaxf(norm, 1e-12f);
  const float ae = E * invn;
  const float ac = C * invn;
  const float an = N * invn;
  const float nc = norm * scale;
  const float re = sqrtf(fmaxf(nc * nc - 2.f * nc * ae + 1.f, 0.f));
  const float rc = sqrtf(fmaxf(nc * nc - 2.f * nc * ac + 1.f, 0.f));
  const float rn = sqrtf(fmaxf(nc * nc - 2.f * nc * an + 1.f, 0.f));
  const float boundary = fminf(fmaxf(1.f - fabsf(ae - ac), 0.f), 1.f);
  f32x4 cf;
  cf.x = 0.1f * (1.f - ae) / fmaxf(re, 1e-12f);
  cf.y = 0.1f * (1.f - ac) / fmaxf(rc, 1e-12f);
  cf.z = (0.05f * (1.f - an) + 0.05f * boundary) / fmaxf(rn, 1e-12f);
  cf.w = scale * (1.f - cf.x - cf.y - cf.z);
  coef[row] = cf;
  scaleArr[row] = scale;
}

// ---------------------------------------------------------------------------
// Per-row stats for fp32 h0 (layer 0 only; also casts h0 -> hb bf16).
// ---------------------------------------------------------------------------
__global__ __launch_bounds__(256) void stats0_kernel(
    const float* __restrict__ src, bf16_t* __restrict__ dstb,
    float* __restrict__ scaleArr, f32x4* __restrict__ coef,
    const float* __restrict__ dirs) {
  const int row = blockIdx.x;
  const int t = threadIdx.x;
  const float4 v = ((const float4*)src)[(size_t)row * 256 + t];
  const float4 e = ((const float4*)dirs)[t];
  const float4 c = ((const float4*)dirs)[t + 256];
  const float4 n = ((const float4*)dirs)[t + 512];
  float ss = v.x * v.x + v.y * v.y + v.z * v.z + v.w * v.w;
  float de = v.x * e.x + v.y * e.y + v.z * e.z + v.w * e.w;
  float dc = v.x * c.x + v.y * c.y + v.z * c.z + v.w * c.w;
  float dn = v.x * n.x + v.y * n.y + v.z * n.z + v.w * n.w;
#pragma unroll
  for (int off = 32; off; off >>= 1) {
    ss += __shfl_down(ss, off);
    de += __shfl_down(de, off);
    dc += __shfl_down(dc, off);
    dn += __shfl_down(dn, off);
  }
  __shared__ float red[4][4];
  const int w = t >> 6;
  if ((t & 63) == 0) {
    red[w][0] = ss; red[w][1] = de; red[w][2] = dc; red[w][3] = dn;
  }
  __syncthreads();
  union { bf16_t b[4]; uint2 u; } pk;
  pk.b[0] = (bf16_t)v.x; pk.b[1] = (bf16_t)v.y;
  pk.b[2] = (bf16_t)v.z; pk.b[3] = (bf16_t)v.w;
  ((uint2*)dstb)[(size_t)row * 256 + t] = pk.u;
  if (t == 0) {
    float S = 0, E = 0, C = 0, N = 0;
#pragma unroll
    for (int i = 0; i < 4; ++i) {
      S += red[i][0]; E += red[i][1]; C += red[i][2]; N += red[i][3];
    }
    const float norm = sqrtf(S);
    const float scale = 1.f;  // no clamp on layer 0 input
    const float invn = 1.f / fmaxf(norm, 1e-12f);
    const float ae = E * invn;
    const float ac = C * invn;
    const float an = N * invn;
    const float nc = norm * scale;
    const float re = sqrtf(fmaxf(nc * nc - 2.f * nc * ae + 1.f, 0.f));
    const float rc = sqrtf(fmaxf(nc * nc - 2.f * nc * ac + 1.f, 0.f));
    const float rn = sqrtf(fmaxf(nc * nc - 2.f * nc * an + 1.f, 0.f));
    const float boundary = fminf(fmaxf(1.f - fabsf(ae - ac), 0.f), 1.f);
    f32x4 cf;
    cf.x = 0.1f * (1.f - ae) / fmaxf(re, 1e-12f);
    cf.y = 0.1f * (1.f - ac) / fmaxf(rc, 1e-12f);
    cf.z = (0.05f * (1.f - an) + 0.05f * boundary) / fmaxf(rn, 1e-12f);
    cf.w = scale * (1.f - cf.x - cf.y - cf.z);
    coef[row] = cf;
    scaleArr[row] = scale;
  }
}

__global__ __launch_bounds__(256) void finalize_kernel(
    float* __restrict__ outF, const float* __restrict__ scaleArr) {
  const int row = blockIdx.x;
  const int t = threadIdx.x;
  const float s = scaleArr[row];
  float4 v = ((float4*)outF)[(size_t)row * 256 + t];
  v.x *= s; v.y *= s; v.z *= s; v.w *= s;
  ((float4*)outF)[(size_t)row * 256 + t] = v;
}

// Normalize anchors -> dirs[3*DIM]
__global__ __launch_bounds__(256) void prep_dirs(
    const float* __restrict__ ae, const float* __restrict__ ac,
    const float* __restrict__ an, float* __restrict__ dirs) {
  const int t = threadIdx.x;
  const float4 a = ((const float4*)ae)[t];
  const float4 b = ((const float4*)ac)[t];
  const float4 c = ((const float4*)an)[t];
  float sa = a.x * a.x + a.y * a.y + a.z * a.z + a.w * a.w;
  float sb = b.x * b.x + b.y * b.y + b.z * b.z + b.w * b.w;
  float sc = c.x * c.x + c.y * c.y + c.z * c.z + c.w * c.w;
#pragma unroll
  for (int off = 32; off; off >>= 1) {
    sa += __shfl_down(sa, off);
    sb += __shfl_down(sb, off);
    sc += __shfl_down(sc, off);
  }
  __shared__ float red[4][3];
  __shared__ float fin[3];
  const int w = t >> 6;
  if ((t & 63) == 0) { red[w][0] = sa; red[w][1] = sb; red[w][2] = sc; }
  __syncthreads();
  if (t == 0) {
    float x = 0, y = 0, z = 0;
#pragma unroll
    for (int i = 0; i < 4; ++i) { x += red[i][0]; y += red[i][1]; z += red[i][2]; }
    fin[0] = x; fin[1] = y; fin[2] = z;
  }
  __syncthreads();
  const float ia = 1.f / fmaxf(sqrtf(fin[0]), 1e-12f);
  const float ib = 1.f / fmaxf(sqrtf(fin[1]), 1e-12f);
  const float ic = 1.f / fmaxf(sqrtf(fin[2]), 1e-12f);
  float4 oa, ob, oc;
  oa.x = a.x * ia; oa.y = a.y * ia; oa.z = a.z * ia; oa.w = a.w * ia;
  ob.x = b.x * ib; ob.y = b.y * ib; ob.z = b.z * ib; ob.w = b.w * ib;
  oc.x = c.x * ic; oc.y = c.y * ic; oc.z = c.z * ic; oc.w = c.w * ic;
  ((float4*)dirs)[t] = oa;
  ((float4*)dirs)[t + 256] = ob;
  ((float4*)dirs)[t + 512] = oc;
}

// Build colpack[col] = {e[col], c[col], n[col], b2[col]}
__global__ __launch_bounds__(256) void prep_cols(
    const float* __restrict__ dirs, const float* __restrict__ b2,
    f32x4* __restrict__ colpack) {
  const int t = threadIdx.x;  // handles cols 4t..4t+3
  const float4 e = ((const float4*)dirs)[t];
  const float4 c = ((const float4*)dirs)[t + 256];
  const float4 n = ((const float4*)dirs)[t + 512];
  const float4 b = ((const float4*)b2)[t];
  f32x4 o;
  o.x = e.x; o.y = c.x; o.z = n.x; o.w = b.x; colpack[4 * t + 0] = o;
  o.x = e.y; o.y = c.y; o.z = n.y; o.w = b.y; colpack[4 * t + 1] = o;
  o.x = e.z; o.y = c.z; o.z = n.z; o.w = b.z; colpack[4 * t + 2] = o;
  o.x = e.w; o.y = c.w; o.z = n.w; o.w = b.w; colpack[4 * t + 3] = o;
}

__global__ __launch_bounds__(256) void cast_w_kernel(
    const float* __restrict__ W, bf16_t* __restrict__ Wb) {
  const int i = blockIdx.x * 256 + threadIdx.x;
  const float4 v = ((const float4*)W)[i];
  union { bf16_t b[4]; uint2 u; } pk;
  pk.b[0] = (bf16_t)v.x; pk.b[1] = (bf16_t)v.y;
  pk.b[2] = (bf16_t)v.z; pk.b[3] = (bf16_t)v.w;
  ((uint2*)Wb)[i] = pk.u;
}

extern "C" void kernel_launch(void* const* d_in, const int* in_sizes, int n_in,
                              void* d_out, int out_size, void* d_ws,
                              size_t ws_size, hipStream_t stream) {
  const float* h0 = (const float*)d_in[0];
  const float* W1 = (const float*)d_in[1];
  const float* b1 = (const float*)d_in[2];
  const float* W2 = (const float*)d_in[3];
  const float* b2 = (const float*)d_in[4];
  const float* ae = (const float*)d_in[5];
  const float* ac = (const float*)d_in[6];
  const float* an = (const float*)d_in[7];
  float* outF = (float*)d_out;

  char* ws = (char*)d_ws;
  bf16_t* hb = (bf16_t*)ws;  ws += (size_t)BATCH * DIM * 2;   // 32 MB
  bf16_t* Tb = (bf16_t*)ws;  ws += (size_t)BATCH * DIM * 2;   // 32 MB
  bf16_t* W1b = (bf16_t*)ws; ws += (size_t)DIM * DIM * 2;     // 2 MB
  bf16_t* W2b = (bf16_t*)ws; ws += (size_t)DIM * DIM * 2;     // 2 MB
  float* dirs = (float*)ws;  ws += 3 * DIM * 4;
  f32x4* colpack = (f32x4*)ws; ws += DIM * 16;
  f32x4* coef = (f32x4*)ws;  ws += (size_t)BATCH * 16;
  float* scaleArr = (float*)ws; ws += (size_t)BATCH * 4;
  float* part = (float*)ws;  ws += (size_t)BATCH * 16 * 16;   // 4 MB

  prep_dirs<<<1, 256, 0, stream>>>(ae, ac, an, dirs);
  prep_cols<<<1, 256, 0, stream>>>(dirs, b2, colpack);
  cast_w_kernel<<<DIM * DIM / 1024, 256, 0, stream>>>(W1, W1b);
  cast_w_kernel<<<DIM * DIM / 1024, 256, 0, stream>>>(W2, W2b);
  stats0_kernel<<<BATCH, 256, 0, stream>>>(h0, hb, scaleArr, coef, dirs);

  dim3 grid(BATCH / 128, DIM / 128);
  for (int l = 0; l < NLAYER; ++l) {
    gemm_kernel<0><<<grid, 256, 0, stream>>>(hb, W1b, b1, Tb, nullptr, nullptr,
                                             nullptr, scaleArr, nullptr,
                                             nullptr);
    if (l < NLAYER - 1) {
      gemm_kernel<1><<<grid, 256, 0, stream>>>(Tb, W2b, b2, hb, nullptr, coef,
                                               colpack, nullptr, hb, part);
      convert_kernel<<<BATCH / 256, 256, 0, stream>>>(part, coef, scaleArr);
    } else {
      gemm_kernel<2><<<grid, 256, 0, stream>>>(Tb, W2b, b2, nullptr, outF, coef,
                                               colpack, nullptr, hb, part);
      convert_kernel<<<BATCH / 256, 256, 0, stream>>>(part, coef, scaleArr);
      finalize_kernel<<<BATCH, 256, 0, stream>>>(outF, scaleArr);
    }
  }
}